// Round 6
// baseline (553.937 us; speedup 1.0000x reference)
//
#include <hip/hip_runtime.h>
#include <hip/hip_fp16.h>

typedef _Float16 f16;
typedef f16 f16x8 __attribute__((ext_vector_type(8)));
typedef float f32x4 __attribute__((ext_vector_type(4)));

#define NDRUG 100000
#define NCELL 20000
#define EDD   1600000
#define EDC   800000
#define ECD   800000
#define NQ    100000
#define ETOT  (EDD + ECD + EDC)
#define CAP_DD 64
#define CAP_CD 64
#define CAP_DC 128

// bucketed build: drug-dst space [0,200000) in 256-node buckets, cell-dst [200000,220000) in 64-node buckets
#define NBD 782
#define NBC 313
#define NBTOT (NBD + NBC)          // 1095
#define ECHUNK 4096
#define NBLK ((ETOT + ECHUNK - 1) / ECHUNK)
#define BCAP 8192                  // fixed global capacity per bucket (mean 4096)
#define LCAP 6144                  // LDS sort capacity per bucket (mean 4096, +32 sigma)

__device__ inline int bucket_of(int rdst) { return rdst < 200000 ? (rdst >> 8) : NBD + ((rdst - 200000) >> 6); }
__device__ inline int dl_of(int rdst)     { return rdst < 200000 ? (rdst & 255) : ((rdst - 200000) & 63); }

// ---------------- K0: init bucket cursors ----------------

__global__ void initcur_k(int* __restrict__ cur)
{
    int i = blockIdx.x * 256 + threadIdx.x;
    if (i < NBTOT) cur[i] = i * BCAP;
}

// ---------------- K1: binned scatter, block-sorted, coalesced writes ----------------

__global__ __launch_bounds__(256) void scatter_k(
    const int* __restrict__ dds, const int* __restrict__ ddd,
    const int* __restrict__ cds, const int* __restrict__ cdd,
    const int* __restrict__ dcs, const int* __restrict__ dcd,
    int* __restrict__ bucket_cur, unsigned* __restrict__ binned)
{
    __shared__ unsigned lrec[ECHUNK];
    __shared__ unsigned short lbkt[ECHUNK];
    __shared__ unsigned short lrank[ECHUNK];
    __shared__ unsigned srec[ECHUNK];
    __shared__ unsigned short sbkt[ECHUNK];
    __shared__ int lh[NBTOT];
    __shared__ int loff[NBTOT];
    __shared__ int lbase[NBTOT];
    __shared__ int seg[256];
    __shared__ int nvalid_sh;

    int tid = threadIdx.x;
    for (int i = tid; i < NBTOT; i += 256) lh[i] = 0;
    __syncthreads();

    int base = blockIdx.x * ECHUNK;
    for (int j = tid; j < ECHUNK; j += 256) {
        int e = base + j;
        if (e < ETOT) {
            int src, rdst;
            if (e < EDD) { src = dds[e]; rdst = ddd[e]; }
            else if (e < EDD + ECD) { int i2 = e - EDD; src = cds[i2]; rdst = 100000 + cdd[i2]; }
            else { int i2 = e - EDD - ECD; src = dcs[i2]; rdst = 200000 + dcd[i2]; }
            int b = bucket_of(rdst);
            lrec[j] = ((unsigned)dl_of(rdst) << 17) | (unsigned)src;
            lbkt[j] = (unsigned short)b;
            lrank[j] = (unsigned short)atomicAdd(&lh[b], 1);
        } else {
            lbkt[j] = 0xFFFFu;
        }
    }
    __syncthreads();

    // block-local exclusive scan of lh -> loff, reserve global runs -> lbase
    int mine[5], s = 0;
#pragma unroll
    for (int q = 0; q < 5; ++q) { int idx = tid * 5 + q; mine[q] = (idx < NBTOT) ? lh[idx] : 0; s += mine[q]; }
    seg[tid] = s; __syncthreads();
    for (int o = 1; o < 256; o <<= 1) {
        int v = (tid >= o) ? seg[tid - o] : 0;
        __syncthreads();
        seg[tid] += v;
        __syncthreads();
    }
    if (tid == 255) nvalid_sh = seg[255];
    int run = seg[tid] - s;
#pragma unroll
    for (int q = 0; q < 5; ++q) {
        int idx = tid * 5 + q;
        if (idx < NBTOT) {
            loff[idx] = run;
            lbase[idx] = mine[q] ? atomicAdd(&bucket_cur[idx], mine[q]) : 0;
        }
        run += mine[q];
    }
    __syncthreads();

    // place into bucket-sorted LDS order
    for (int j = tid; j < ECHUNK; j += 256) {
        int b = lbkt[j];
        if (b != 0xFFFF) {
            int p = loff[b] + lrank[j];
            srec[p] = lrec[j];
            sbkt[p] = (unsigned short)b;
        }
    }
    __syncthreads();

    // linear write: consecutive p -> consecutive addresses within each bucket run
    int nvalid = nvalid_sh;
    for (int p = tid; p < nvalid; p += 256) {
        int b = sbkt[p];
        binned[lbase[b] + (p - loff[b])] = srec[p];
    }
}

// ---------------- K2: per-bucket counting sort -> per-node lists + counts ----------------

__global__ __launch_bounds__(256) void bucket_build_k(
    const unsigned* __restrict__ binned, const int* __restrict__ bucket_cur,
    int* __restrict__ cnt_dd, int* __restrict__ cnt_cd, int* __restrict__ cnt_dc,
    int* __restrict__ l_dd, int* __restrict__ l_cd, int* __restrict__ l_dc)
{
    __shared__ int cnt[256];
    __shared__ int off[256];
    __shared__ int seg[256];
    __shared__ unsigned short lrank[LCAP];
    __shared__ unsigned srec[LCAP];

    int b = blockIdx.x, tid = threadIdx.x;
    int gbase = b * BCAP;
    int n = bucket_cur[b] - gbase;
    n = n < 0 ? 0 : (n > LCAP ? LCAP : n);

    cnt[tid] = 0;
    __syncthreads();
    for (int j = tid; j < n; j += 256) {
        unsigned r = binned[gbase + j];
        lrank[j] = (unsigned short)atomicAdd(&cnt[r >> 17], 1);
    }
    __syncthreads();
    int c = cnt[tid];
    seg[tid] = c; __syncthreads();
    for (int o = 1; o < 256; o <<= 1) {
        int v = (tid >= o) ? seg[tid - o] : 0;
        __syncthreads();
        seg[tid] += v;
        __syncthreads();
    }
    off[tid] = seg[tid] - c;
    __syncthreads();

    // node-sorted order in LDS (binned re-read is an L2 hit)
    for (int j = tid; j < n; j += 256) {
        unsigned r = binned[gbase + j];
        int p = off[r >> 17] + lrank[j];
        srec[p] = r;
    }
    __syncthreads();

    // linear write: each node's run is contiguous
    for (int p = tid; p < n; p += 256) {
        unsigned r = srec[p];
        int dl = r >> 17;
        int rank = p - off[dl];
        int src = r & 0x1FFFF;
        if (b < NBD) {
            int rdst = b * 256 + dl;
            if (rdst < 100000) { if (rank < CAP_DD) l_dd[(size_t)rdst * CAP_DD + rank] = src; }
            else               { if (rank < CAP_CD) l_cd[(size_t)(rdst - 100000) * CAP_CD + rank] = src; }
        } else {
            int node = (b - NBD) * 64 + dl;
            if (rank < CAP_DC) l_dc[(size_t)node * CAP_DC + rank] = src;
        }
    }

    // per-node counts (each node covered exactly once across the grid)
    if (b < NBD) {
        int rdst = b * 256 + tid;
        if (rdst < 200000) {
            if (rdst < 100000) cnt_dd[rdst] = cnt[tid];
            else               cnt_cd[rdst - 100000] = cnt[tid];
        }
    } else {
        if (tid < 64) {
            int node = (b - NBD) * 64 + tid;
            if (node < NCELL) cnt_dc[node] = cnt[tid];
        }
    }
}

// ---------------- merged mean aggregation: all 3 edge types, fp16 rows, 8-deep ----------------

__device__ inline void addv(float* acc, uint4 v)
{
    const __half2* h = (const __half2*)&v;
#pragma unroll
    for (int j = 0; j < 4; ++j) {
        float2 f = __half22float2(h[j]);
        acc[2 * j]     += f.x;
        acc[2 * j + 1] += f.y;
    }
}

__global__ __launch_bounds__(256) void agg_all_k(
    const __half* __restrict__ t_d, const __half* __restrict__ t_c,
    const int* __restrict__ cnt_dd, const int* __restrict__ cnt_cd, const int* __restrict__ cnt_dc,
    const int* __restrict__ l_dd, const int* __restrict__ l_cd, const int* __restrict__ l_dc,
    __half* __restrict__ m_a, __half* __restrict__ m_b, __half* __restrict__ m_c)
{
    int node = blockIdx.x * 16 + (threadIdx.x >> 4);
    int g = threadIdx.x & 15;                 // 8-channel group

    const int* list; int n; const __half* tab; __half* out;
    if (node < NDRUG) {
        list = l_dd + (size_t)node * CAP_DD; n = cnt_dd[node];
        if (n > CAP_DD) n = CAP_DD;
        tab = t_d; out = m_a + (size_t)node * 128;
    } else if (node < 2 * NDRUG) {
        int m = node - NDRUG;
        list = l_cd + (size_t)m * CAP_CD; n = cnt_cd[m];
        if (n > CAP_CD) n = CAP_CD;
        tab = t_c; out = m_b + (size_t)m * 128;
    } else if (node < 2 * NDRUG + NCELL) {
        int m = node - 2 * NDRUG;
        list = l_dc + (size_t)m * CAP_DC; n = cnt_dc[m];
        if (n > CAP_DC) n = CAP_DC;
        tab = t_d; out = m_c + (size_t)m * 128;
    } else return;

    const __half* base = tab + (size_t)g * 8;

    float acc[8];
#pragma unroll
    for (int j = 0; j < 8; ++j) acc[j] = 0.f;

    int i = 0;
    for (; i + 7 < n; i += 8) {
        uint4 v[8];
#pragma unroll
        for (int u = 0; u < 8; ++u) v[u] = *(const uint4*)(base + (size_t)list[i + u] * 128);
#pragma unroll
        for (int u = 0; u < 8; ++u) addv(acc, v[u]);
    }
    for (; i + 3 < n; i += 4) {
        uint4 v0 = *(const uint4*)(base + (size_t)list[i] * 128);
        uint4 v1 = *(const uint4*)(base + (size_t)list[i + 1] * 128);
        uint4 v2 = *(const uint4*)(base + (size_t)list[i + 2] * 128);
        uint4 v3 = *(const uint4*)(base + (size_t)list[i + 3] * 128);
        addv(acc, v0); addv(acc, v1); addv(acc, v2); addv(acc, v3);
    }
    for (; i < n; ++i) {
        uint4 v = *(const uint4*)(base + (size_t)list[i] * 128);
        addv(acc, v);
    }

    float inv = 1.f / fmaxf((float)n, 1.f);
    __half h[8];
#pragma unroll
    for (int j = 0; j < 8; ++j) h[j] = __float2half(acc[j] * inv);
    *(uint4*)(out + g * 8) = *(uint4*)h;
}

// ---------------- prep: fp32 -> fp16 weights, summed root weights / biases ----------------

__global__ __launch_bounds__(256) void prep_k(
    const float* __restrict__ wd,     const float* __restrict__ wc,     const float* __restrict__ m1w,
    const float* __restrict__ dd1_wl, const float* __restrict__ cd1_wl, const float* __restrict__ dc1_wl,
    const float* __restrict__ dc1_wr, const float* __restrict__ dd1_wr, const float* __restrict__ cd1_wr,
    const float* __restrict__ dd1_bl, const float* __restrict__ cd1_bl,
    const float* __restrict__ dd2_wl, const float* __restrict__ cd2_wl, const float* __restrict__ dc2_wl,
    const float* __restrict__ dc2_wr, const float* __restrict__ dd2_wr, const float* __restrict__ cd2_wr,
    const float* __restrict__ dd2_bl, const float* __restrict__ cd2_bl,
    f16* __restrict__ wd16, f16* __restrict__ wc16, f16* __restrict__ m1w16,
    f16* __restrict__ dd1_wl16, f16* __restrict__ cd1_wl16, f16* __restrict__ dc1_wl16,
    f16* __restrict__ dc1_wr16, f16* __restrict__ wr1s16,
    f16* __restrict__ dd2_wl16, f16* __restrict__ cd2_wl16, f16* __restrict__ dc2_wl16,
    f16* __restrict__ dc2_wr16, f16* __restrict__ wr2s16,
    float* __restrict__ bsum1, float* __restrict__ bsum2)
{
    int i = blockIdx.x * 256 + threadIdx.x;
    if (i < 128 * 256) wd16[i] = (f16)wd[i];
    if (i < 128 * 512) wc16[i] = (f16)wc[i];
    if (i < 128 * 384) m1w16[i] = (f16)m1w[i];
    if (i < 128 * 128) {
        dd1_wl16[i] = (f16)dd1_wl[i];
        cd1_wl16[i] = (f16)cd1_wl[i];
        dc1_wl16[i] = (f16)dc1_wl[i];
        dc1_wr16[i] = (f16)dc1_wr[i];
        wr1s16[i]   = (f16)(dd1_wr[i] + cd1_wr[i]);
        dd2_wl16[i] = (f16)dd2_wl[i];
        cd2_wl16[i] = (f16)cd2_wl[i];
        dc2_wl16[i] = (f16)dc2_wl[i];
        dc2_wr16[i] = (f16)dc2_wr[i];
        wr2s16[i]   = (f16)(dd2_wr[i] + cd2_wr[i]);
    }
    if (i < 128) {
        bsum1[i] = dd1_bl[i] + cd1_bl[i];
        bsum2[i] = dd2_bl[i] + cd2_bl[i];
    }
}

// ---------------- MFMA GEMM: C[M,128] = sum_s A_s[M,Ks] @ W_s[128,Ks]^T + bias ----------------
// 128x128 C-tile per block, 4 waves x 32 rows, BK=64, fp16 inputs, fp32 accum.
// MODE 0: fp16 store; MODE 1: relu + fp16 store; MODE 2: relu + dot(m2w) + m2b -> Cf[M].

template<typename AT, int MODE>
__global__ __launch_bounds__(256) void mgemm_k(
    const AT* __restrict__ A0, const int* __restrict__ I0, const f16* __restrict__ W0, int K0, int S0,
    const AT* __restrict__ A1, const int* __restrict__ I1, const f16* __restrict__ W1, int K1, int S1,
    const AT* __restrict__ A2, const int* __restrict__ I2, const f16* __restrict__ W2, int K2, int S2,
    const float* __restrict__ bias, const float* __restrict__ m2w, const float* __restrict__ m2b,
    f16* __restrict__ Ch, float* __restrict__ Cf, int M)
{
    __shared__ f16 As[128][72];   // +8 pad: 144B row stride -> 2-way bank alias (free)
    __shared__ f16 Ws[128][72];

    const int tid = threadIdx.x;
    const int w  = tid >> 6;       // wave 0..3, owns rows [32w, 32w+32)
    const int l  = tid & 63;
    const int lc = l & 15;         // col within 16
    const int lq = l >> 4;         // quarter
    const int mb = blockIdx.x * 128;
    const int sr = tid >> 1;       // staging row 0..127
    const int sk = (tid & 1) * 32; // staging k-offset (f16 elems)

    f32x4 acc[2][8];
#pragma unroll
    for (int mi = 0; mi < 2; ++mi)
#pragma unroll
        for (int j = 0; j < 8; ++j) acc[mi][j] = (f32x4){0.f, 0.f, 0.f, 0.f};

    const AT*  Aseg[3] = {A0, A1, A2};
    const int* Iseg[3] = {I0, I1, I2};
    const f16* Wseg[3] = {W0, W1, W2};
    const int  Kseg[3] = {K0, K1, K2};
    const int  Sseg[3] = {S0, S1, S2};

    for (int s = 0; s < 3; ++s) {
        const AT* A = Aseg[s];
        if (!A) continue;
        const int* idx = Iseg[s];
        const f16* W = Wseg[s];
        const int K = Kseg[s], S = Sseg[s];

        int m = mb + sr; if (m >= M) m = M - 1;
        const AT*  arow = A + (size_t)(idx ? idx[m] : m) * (size_t)K;
        const f16* wrow = W + (size_t)sr * (size_t)S;

        for (int kt = 0; kt < K; kt += 64) {
            // ---- stage A tile (128 x 64 f16), 32 f16 per thread ----
            if constexpr (sizeof(AT) == 2) {
                const uint4* ap = (const uint4*)(arow + kt + sk);
                uint4 a0 = ap[0], a1 = ap[1], a2 = ap[2], a3 = ap[3];
                *(uint4*)&As[sr][sk]      = a0;
                *(uint4*)&As[sr][sk + 8]  = a1;
                *(uint4*)&As[sr][sk + 16] = a2;
                *(uint4*)&As[sr][sk + 24] = a3;
            } else {
                const float4* ap = (const float4*)(arow + kt + sk);
#pragma unroll
                for (int i = 0; i < 4; ++i) {
                    float4 u = ap[2 * i], v = ap[2 * i + 1];
                    f16x8 h;
                    h[0] = (f16)u.x; h[1] = (f16)u.y; h[2] = (f16)u.z; h[3] = (f16)u.w;
                    h[4] = (f16)v.x; h[5] = (f16)v.y; h[6] = (f16)v.z; h[7] = (f16)v.w;
                    *(f16x8*)&As[sr][sk + 8 * i] = h;
                }
            }
            // ---- stage W tile (128 x 64 f16) ----
            {
                const uint4* wp = (const uint4*)(wrow + kt + sk);
                uint4 w0 = wp[0], w1 = wp[1], w2 = wp[2], w3 = wp[3];
                *(uint4*)&Ws[sr][sk]      = w0;
                *(uint4*)&Ws[sr][sk + 8]  = w1;
                *(uint4*)&Ws[sr][sk + 16] = w2;
                *(uint4*)&Ws[sr][sk + 24] = w3;
            }
            __syncthreads();

#pragma unroll
            for (int ks = 0; ks < 64; ks += 32) {
                f16x8 a0 = *(const f16x8*)&As[32 * w + lc][ks + 8 * lq];
                f16x8 a1 = *(const f16x8*)&As[32 * w + 16 + lc][ks + 8 * lq];
#pragma unroll
                for (int j = 0; j < 8; ++j) {
                    f16x8 b = *(const f16x8*)&Ws[16 * j + lc][ks + 8 * lq];
                    acc[0][j] = __builtin_amdgcn_mfma_f32_16x16x32_f16(a0, b, acc[0][j], 0, 0, 0);
                    acc[1][j] = __builtin_amdgcn_mfma_f32_16x16x32_f16(a1, b, acc[1][j], 0, 0, 0);
                }
            }
            __syncthreads();
        }
    }

    // ---- epilogue ----
    // C/D layout per MFMA frag: col = lc + 16j, row = 32w + 16mi + 4*lq + r
    if (MODE == 2) {
        float part[2][4];
#pragma unroll
        for (int mi = 0; mi < 2; ++mi)
#pragma unroll
            for (int r = 0; r < 4; ++r) part[mi][r] = 0.f;
#pragma unroll
        for (int j = 0; j < 8; ++j) {
            float bj = bias[16 * j + lc];
            float wv = m2w[16 * j + lc];
#pragma unroll
            for (int mi = 0; mi < 2; ++mi)
#pragma unroll
                for (int r = 0; r < 4; ++r) {
                    float v = acc[mi][j][r] + bj;
                    v = v > 0.f ? v : 0.f;
                    part[mi][r] = fmaf(v, wv, part[mi][r]);
                }
        }
#pragma unroll
        for (int mi = 0; mi < 2; ++mi)
#pragma unroll
            for (int r = 0; r < 4; ++r) {
                float p = part[mi][r];
#pragma unroll
                for (int o = 1; o < 16; o <<= 1) p += __shfl_xor(p, o, 16);
                if (lc == 0) {
                    int row = mb + 32 * w + 16 * mi + 4 * lq + r;
                    if (row < M) Cf[row] = p + m2b[0];
                }
            }
    } else {
#pragma unroll
        for (int j = 0; j < 8; ++j) {
            float bj = bias[16 * j + lc];
#pragma unroll
            for (int mi = 0; mi < 2; ++mi)
#pragma unroll
                for (int r = 0; r < 4; ++r) {
                    float v = acc[mi][j][r] + bj;
                    if (MODE == 1) v = v > 0.f ? v : 0.f;
                    int row = mb + 32 * w + 16 * mi + 4 * lq + r;
                    if (row < M) Ch[(size_t)row * 128 + 16 * j + lc] = (f16)v;
                }
        }
    }
}

// ---------------- launch ----------------

extern "C" void kernel_launch(void* const* d_in, const int* in_sizes, int n_in,
                              void* d_out, int out_size, void* d_ws, size_t ws_size,
                              hipStream_t stream)
{
    const float* x_drug = (const float*)d_in[0];
    const float* x_cell = (const float*)d_in[1];
    const int* ei_dd_src = (const int*)d_in[2];
    const int* ei_dd_dst = (const int*)d_in[3];
    const int* ei_dc_src = (const int*)d_in[4];
    const int* ei_dc_dst = (const int*)d_in[5];
    const int* ei_cd_src = (const int*)d_in[6];
    const int* ei_cd_dst = (const int*)d_in[7];
    const int* q_da = (const int*)d_in[8];
    const int* q_db = (const int*)d_in[9];
    const int* q_c  = (const int*)d_in[10];
    const float* wd = (const float*)d_in[11];
    const float* bd = (const float*)d_in[12];
    const float* wc = (const float*)d_in[13];
    const float* bc = (const float*)d_in[14];
    const float* dd1_wl = (const float*)d_in[15]; const float* dd1_bl = (const float*)d_in[16]; const float* dd1_wr = (const float*)d_in[17];
    const float* cd1_wl = (const float*)d_in[18]; const float* cd1_bl = (const float*)d_in[19]; const float* cd1_wr = (const float*)d_in[20];
    const float* dc1_wl = (const float*)d_in[21]; const float* dc1_bl = (const float*)d_in[22]; const float* dc1_wr = (const float*)d_in[23];
    const float* dd2_wl = (const float*)d_in[24]; const float* dd2_bl = (const float*)d_in[25]; const float* dd2_wr = (const float*)d_in[26];
    const float* cd2_wl = (const float*)d_in[27]; const float* cd2_bl = (const float*)d_in[28]; const float* cd2_wr = (const float*)d_in[29];
    const float* dc2_wl = (const float*)d_in[30]; const float* dc2_bl = (const float*)d_in[31]; const float* dc2_wr = (const float*)d_in[32];
    const float* m1_w = (const float*)d_in[33]; const float* m1_b = (const float*)d_in[34];
    const float* m2_w = (const float*)d_in[35]; const float* m2_b = (const float*)d_in[36];
    float* out = (float*)d_out;

    char* wsp = (char*)d_ws;
    size_t off = 0;
    auto alloc = [&](size_t bytes) -> void* {
        void* p = wsp + off;
        off += (bytes + 255) & ~(size_t)255;
        return p;
    };

    __half* xd_h     = (__half*)alloc((size_t)NDRUG * 128 * 2);
    __half* xc_h     = (__half*)alloc((size_t)NCELL * 128 * 2);
    __half* hd_h     = (__half*)alloc((size_t)NDRUG * 128 * 2);
    __half* hc_h     = (__half*)alloc((size_t)NCELL * 128 * 2);
    __half* mean_a_h = (__half*)alloc((size_t)NDRUG * 128 * 2);
    __half* mean_b_h = (__half*)alloc((size_t)NDRUG * 128 * 2);
    __half* mean_c_h = (__half*)alloc((size_t)NCELL * 128 * 2);
    __half* od_h     = (__half*)alloc((size_t)NDRUG * 128 * 2);
    __half* oc_h     = (__half*)alloc((size_t)NCELL * 128 * 2);

    f16* wd16     = (f16*)alloc(128 * 256 * 2);
    f16* wc16     = (f16*)alloc(128 * 512 * 2);
    f16* m1w16    = (f16*)alloc(128 * 384 * 2);
    f16* dd1_wl16 = (f16*)alloc(128 * 128 * 2);
    f16* cd1_wl16 = (f16*)alloc(128 * 128 * 2);
    f16* dc1_wl16 = (f16*)alloc(128 * 128 * 2);
    f16* dc1_wr16 = (f16*)alloc(128 * 128 * 2);
    f16* wr1s16   = (f16*)alloc(128 * 128 * 2);
    f16* dd2_wl16 = (f16*)alloc(128 * 128 * 2);
    f16* cd2_wl16 = (f16*)alloc(128 * 128 * 2);
    f16* dc2_wl16 = (f16*)alloc(128 * 128 * 2);
    f16* dc2_wr16 = (f16*)alloc(128 * 128 * 2);
    f16* wr2s16   = (f16*)alloc(128 * 128 * 2);
    float* bsum1  = (float*)alloc(128 * 4);
    float* bsum2  = (float*)alloc(128 * 4);

    int* cnt      = (int*)alloc((size_t)(2 * NDRUG + NCELL) * 4);
    int* cnt_dd   = cnt;
    int* cnt_cd   = cnt + NDRUG;
    int* cnt_dc   = cnt + 2 * NDRUG;
    int* l_dd     = (int*)alloc((size_t)NDRUG * CAP_DD * 4);
    int* l_cd     = (int*)alloc((size_t)NDRUG * CAP_CD * 4);
    int* l_dc     = (int*)alloc((size_t)NCELL * CAP_DC * 4);

    int* bucket_cur  = (int*)alloc((size_t)NBTOT * 4);
    unsigned* binned = (unsigned*)alloc((size_t)NBTOT * BCAP * 4);

    // ---- binned adjacency build (fixed-capacity buckets; no hist/scan) ----
    initcur_k<<<(NBTOT + 255) / 256, 256, 0, stream>>>(bucket_cur);
    scatter_k<<<NBLK, 256, 0, stream>>>(ei_dd_src, ei_dd_dst, ei_cd_src, ei_cd_dst,
                                        ei_dc_src, ei_dc_dst, bucket_cur, binned);
    bucket_build_k<<<NBTOT, 256, 0, stream>>>(binned, bucket_cur,
                                              cnt_dd, cnt_cd, cnt_dc, l_dd, l_cd, l_dc);

    prep_k<<<256, 256, 0, stream>>>(
        wd, wc, m1_w,
        dd1_wl, cd1_wl, dc1_wl, dc1_wr, dd1_wr, cd1_wr, dd1_bl, cd1_bl,
        dd2_wl, cd2_wl, dc2_wl, dc2_wr, dd2_wr, cd2_wr, dd2_bl, cd2_bl,
        wd16, wc16, m1w16,
        dd1_wl16, cd1_wl16, dc1_wl16, dc1_wr16, wr1s16,
        dd2_wl16, cd2_wl16, dc2_wl16, dc2_wr16, wr2s16,
        bsum1, bsum2);

    const f16*   fnull = nullptr;
    const float* f32null = nullptr;
    const int*   inull = nullptr;
    const int GD = (NDRUG + 127) / 128;
    const int GC = (NCELL + 127) / 128;
    const int GQ = (NQ + 127) / 128;

    // input projections -> fp16 feature tables
    mgemm_k<float, 0><<<GD, 256, 0, stream>>>(
        x_drug, inull, wd16, 256, 256,
        f32null, inull, fnull, 0, 0,
        f32null, inull, fnull, 0, 0,
        bd, f32null, f32null, (f16*)xd_h, nullptr, NDRUG);
    mgemm_k<float, 0><<<GC, 256, 0, stream>>>(
        x_cell, inull, wc16, 512, 512,
        f32null, inull, fnull, 0, 0,
        f32null, inull, fnull, 0, 0,
        bc, f32null, f32null, (f16*)xc_h, nullptr, NCELL);

    const int AGG_GRID = (2 * NDRUG + NCELL + 15) / 16;

    // layer 1 aggregation (merged, fp16 gathers)
    agg_all_k<<<AGG_GRID, 256, 0, stream>>>(xd_h, xc_h, cnt_dd, cnt_cd, cnt_dc,
                                            l_dd, l_cd, l_dc, mean_a_h, mean_b_h, mean_c_h);

    // layer 1 GEMMs -> fp16 h tables
    mgemm_k<f16, 1><<<GD, 256, 0, stream>>>(
        (const f16*)mean_a_h, inull, dd1_wl16, 128, 128,
        (const f16*)mean_b_h, inull, cd1_wl16, 128, 128,
        (const f16*)xd_h,     inull, wr1s16,   128, 128,
        bsum1, f32null, f32null, (f16*)hd_h, nullptr, NDRUG);
    mgemm_k<f16, 1><<<GC, 256, 0, stream>>>(
        (const f16*)mean_c_h, inull, dc1_wl16, 128, 128,
        (const f16*)xc_h,     inull, dc1_wr16, 128, 128,
        fnull,                inull, fnull,    0, 0,
        dc1_bl, f32null, f32null, (f16*)hc_h, nullptr, NCELL);

    // layer 2 aggregation
    agg_all_k<<<AGG_GRID, 256, 0, stream>>>(hd_h, hc_h, cnt_dd, cnt_cd, cnt_dc,
                                            l_dd, l_cd, l_dc, mean_a_h, mean_b_h, mean_c_h);

    // layer 2 GEMMs -> fp16 od/oc
    mgemm_k<f16, 0><<<GD, 256, 0, stream>>>(
        (const f16*)mean_a_h, inull, dd2_wl16, 128, 128,
        (const f16*)mean_b_h, inull, cd2_wl16, 128, 128,
        (const f16*)hd_h,     inull, wr2s16,   128, 128,
        bsum2, f32null, f32null, (f16*)od_h, nullptr, NDRUG);
    mgemm_k<f16, 0><<<GC, 256, 0, stream>>>(
        (const f16*)mean_c_h, inull, dc2_wl16, 128, 128,
        (const f16*)hc_h,     inull, dc2_wr16, 128, 128,
        fnull,                inull, fnull,    0, 0,
        dc2_bl, f32null, f32null, (f16*)oc_h, nullptr, NCELL);

    // fused head: gather + [B,384]@[384,128]^T + relu + dot(m2_w) + m2_b
    mgemm_k<f16, 2><<<GQ, 256, 0, stream>>>(
        (const f16*)od_h, q_da, m1w16,       128, 384,
        (const f16*)od_h, q_db, m1w16 + 128, 128, 384,
        (const f16*)oc_h, q_c,  m1w16 + 256, 128, 384,
        m1_b, m2_w, m2_b, nullptr, out, NQ);
}